// Round 7
// baseline (178.277 us; speedup 1.0000x reference)
//
#include <hip/hip_runtime.h>

// VQ-VAE codebook quantization — MFMA-screened, np-bit-exact (absmax 0, R6).
// Screen: split-bf16 (xh+xl)(ch+cl) via mfma_f32_16x16x32_bf16, 3 terms.
// Sound window W flags possible np-argmin ambiguity (~1-2% of positions);
// flagged positions re-scanned with the R2-verified exact np fp32 pipeline.
//
// R7: phase 3 software-pipelined — B fragments staged in 8x16KB groups,
// double-buffered in the dead x-stage LDS via async global_load_lds(16B);
// __syncthreads' implicit vmcnt drain is the wait (loads issued 4 tiles
// early). MFMA restructured: three independent 2-chains per rt (was one
// 6-chain) + vector adds -> 3x matrix-pipe ILP.

typedef short bf16x8 __attribute__((ext_vector_type(8)));
typedef float f32x4  __attribute__((ext_vector_type(4)));

#define KCODES 512
#define DDIM 64
#define HWSZ 4096
#define NPOS 131072
#define POSB 128             // positions per block
#define NBLK (NPOS / POSB)   // 1024
#define OUT2_OFF 8388608
#define S_X 129              // x_lds pos-stride in floats (bank-spread)

__device__ __forceinline__ unsigned short f2bf_rne(float f) {
    unsigned u = __builtin_bit_cast(unsigned, f);
    unsigned r = u + 0x7FFFu + ((u >> 16) & 1u);
    return (unsigned short)(r >> 16);
}
__device__ __forceinline__ float bf2f(unsigned short h) {
    unsigned u = ((unsigned)h) << 16;
    return __builtin_bit_cast(float, u);
}

// Async global->LDS 16B: per-lane global addr, wave-uniform LDS base
// (HW scatters lane i at base + i*16).
__device__ __forceinline__ void async_cp16(const void* g, void* l) {
    __builtin_amdgcn_global_load_lds(
        (const __attribute__((address_space(1))) unsigned int*)g,
        (__attribute__((address_space(3))) unsigned int*)l, 16, 0, 0);
}

// numpy pairwise_sum (n=64 branch) of rounded squares, fp32, no fma.
__device__ __forceinline__ float np_sumsq64(const float* __restrict__ a) {
#pragma clang fp contract(off)
    float r0 = a[0]*a[0], r1 = a[1]*a[1], r2 = a[2]*a[2], r3 = a[3]*a[3];
    float r4 = a[4]*a[4], r5 = a[5]*a[5], r6 = a[6]*a[6], r7 = a[7]*a[7];
#pragma unroll
    for (int i = 8; i < 64; i += 8) {
        r0 += a[i+0]*a[i+0]; r1 += a[i+1]*a[i+1];
        r2 += a[i+2]*a[i+2]; r3 += a[i+3]*a[i+3];
        r4 += a[i+4]*a[i+4]; r5 += a[i+5]*a[i+5];
        r6 += a[i+6]*a[i+6]; r7 += a[i+7]*a[i+7];
    }
    return ((r0+r1)+(r2+r3)) + ((r4+r5)+(r6+r7));
}

// Prep: B-fragments (split bf16) in exact 16x16x32 B-operand layout + np cbsqr.
// ws layout: [0,128KB) bf16 frags [tile32][chunk2][split2][lane64][j8];
//            [128KB,130KB) fp32 cbsqr[512].
__global__ __launch_bounds__(256) void vq_prep(
    const float* __restrict__ cb, unsigned short* __restrict__ wsb,
    float* __restrict__ wscb)
{
    if (blockIdx.x < 128) {
        int u = blockIdx.x * 256 + threadIdx.x;   // u = k*64 + d
        int k = u >> 6, d = u & 63;
        float c = cb[u];
        unsigned short ch = f2bf_rne(c);
        float clf = c - bf2f(ch);                  // exact
        unsigned short cl = f2bf_rne(clf);
        int tile = k >> 4, n = k & 15;
        int chunk = d >> 5, quad = (d >> 3) & 3, j = d & 7;
        int lane = quad * 16 + n;                  // B: lane holds B[k=q*8+j][n]
        size_t base = ((((size_t)tile*2 + chunk)*2 + 0)*64 + lane)*8 + j;
        wsb[base]       = (unsigned short)ch;
        wsb[base + 512] = (unsigned short)cl;      // split stride = 64*8
    } else {
        int k = (blockIdx.x - 128) * 256 + threadIdx.x;
        if (k < KCODES) wscb[k] = np_sumsq64(cb + k * DDIM);
    }
}

__global__ __launch_bounds__(256, 4) void vq_main(
    const float* __restrict__ z, const float* __restrict__ cb,
    const unsigned short* __restrict__ wsb, const float* __restrict__ wscb,
    float* __restrict__ out)
{
#pragma clang fp contract(off)
    __shared__ float s_regA[64 * S_X];   // 33 KB: x-stage, then 2x16KB B bufs
    __shared__ float s_cbsqr[KCODES];
    __shared__ float s_xsqr[POSB];
    __shared__ float s_part[2 * POSB];
    __shared__ int   s_idx[POSB];
    __shared__ int   s_flist[POSB];
    __shared__ int   s_cnt;

    const int tid = threadIdx.x;
    const int wv = tid >> 6, ln = tid & 63;
    const int m = ln & 15, q = ln >> 4;
    const int n0 = blockIdx.x * POSB;
    const long gbase = (long)(n0 >> 12) * (DDIM * HWSZ) + (n0 & 4095);

    if (tid == 0) s_cnt = 0;
    s_cbsqr[tid] = wscb[tid];
    s_cbsqr[tid + 256] = wscb[tid + 256];

    // ---- phase 1: z -> x_lds, d-major [d][pos], coalesced ----
#pragma unroll
    for (int i = 0; i < 32; ++i) {
        int d = wv * 16 + (i & 15), ph = i >> 4;
        s_regA[d * S_X + ph * 64 + ln] = z[gbase + (long)d * HWSZ + ph * 64 + ln];
    }
    __syncthreads();

    // ---- phase 2a: np xsqr partials (thread -> (p, h)) ----
    {
        int p = tid & 127, h = tid >> 7;
        float r0 = 0.f, r1 = 0.f, r2 = 0.f, r3 = 0.f;
#pragma unroll
        for (int i = 0; i < 8; ++i) {
            float a0 = s_regA[(8*i + 4*h + 0) * S_X + p];
            float a1 = s_regA[(8*i + 4*h + 1) * S_X + p];
            float a2 = s_regA[(8*i + 4*h + 2) * S_X + p];
            float a3 = s_regA[(8*i + 4*h + 3) * S_X + p];
            r0 += a0*a0; r1 += a1*a1; r2 += a2*a2; r3 += a3*a3;
        }
        s_part[h * POSB + p] = (r0 + r1) + (r2 + r3);
    }

    // ---- phase 2b: A-fragments (per wave: 2 row-tiles x 2 K-chunks, split) ----
    bf16x8 Ah[4], Al[4];
#pragma unroll
    for (int rt = 0; rt < 2; ++rt)
#pragma unroll
        for (int c = 0; c < 2; ++c) {
            int pos = wv * 32 + rt * 16 + m;
            bf16x8 ah, al;
#pragma unroll
            for (int j = 0; j < 8; ++j) {
                float xv = s_regA[(c*32 + q*8 + j) * S_X + pos];
                unsigned short hh = f2bf_rne(xv);
                float lo = xv - bf2f(hh);          // exact
                ah[j] = (short)hh;
                al[j] = (short)f2bf_rne(lo);
            }
            Ah[rt*2 + c] = ah; Al[rt*2 + c] = al;
        }
    __syncthreads();   // x-stage reads done; s_regA reusable as B buffers
    if (tid < POSB) s_xsqr[tid] = s_part[tid] + s_part[POSB + tid]; // np (A+B)

    // ---- phase 3: screen 512 codes; 8 groups x 4 tiles, double-buffered ----
    // Group g (16 KB) staged async into buf[g&1]; loads for g+1 issued before
    // computing g; __syncthreads' vmcnt drain completes them.
    float m1[8], m2[8]; int t1[8];
#pragma unroll
    for (int i = 0; i < 8; ++i) { m1[i] = 3.4e38f; m2[i] = 3.4e38f; t1[i] = 0; }

    // stage group 0 into buf 0
    {
        const float4* src = (const float4*)wsb + 0 * 1024;
        char* dstb = (char*)s_regA + (wv * 64) * 16;
#pragma unroll
        for (int i = 0; i < 4; ++i)
            async_cp16(src + i * 256 + tid, dstb + i * 4096);
    }
    __syncthreads();   // drains vmcnt -> group 0 resident

    for (int g = 0; g < 8; ++g) {
        if (g < 7) {   // prefetch next group into the other buffer
            const float4* src = (const float4*)wsb + (g + 1) * 1024;
            char* dstb = (char*)s_regA + ((g + 1) & 1) * 16384 + (wv * 64) * 16;
#pragma unroll
            for (int i = 0; i < 4; ++i)
                async_cp16(src + i * 256 + tid, dstb + i * 4096);
        }
        const unsigned short* sb =
            (const unsigned short*)s_regA + (g & 1) * 8192;
#pragma unroll 2
        for (int ti = 0; ti < 4; ++ti) {
            int t = g * 4 + ti;
            bf16x8 Bh0 = *(const bf16x8*)(sb + ((ti*2+0)*2+0)*512 + ln*8);
            bf16x8 Bl0 = *(const bf16x8*)(sb + ((ti*2+0)*2+1)*512 + ln*8);
            bf16x8 Bh1 = *(const bf16x8*)(sb + ((ti*2+1)*2+0)*512 + ln*8);
            bf16x8 Bl1 = *(const bf16x8*)(sb + ((ti*2+1)*2+1)*512 + ln*8);
            float cbv = s_cbsqr[t * 16 + m];
#pragma unroll
            for (int rt = 0; rt < 2; ++rt) {
                const f32x4 zac = {0.f, 0.f, 0.f, 0.f};
                f32x4 aP = __builtin_amdgcn_mfma_f32_16x16x32_bf16(Al[rt*2+0], Bh0, zac, 0,0,0);
                f32x4 aQ = __builtin_amdgcn_mfma_f32_16x16x32_bf16(Ah[rt*2+0], Bl0, zac, 0,0,0);
                f32x4 aR = __builtin_amdgcn_mfma_f32_16x16x32_bf16(Ah[rt*2+0], Bh0, zac, 0,0,0);
                aP = __builtin_amdgcn_mfma_f32_16x16x32_bf16(Al[rt*2+1], Bh1, aP, 0,0,0);
                aQ = __builtin_amdgcn_mfma_f32_16x16x32_bf16(Ah[rt*2+1], Bl1, aQ, 0,0,0);
                aR = __builtin_amdgcn_mfma_f32_16x16x32_bf16(Ah[rt*2+1], Bh1, aR, 0,0,0);
                f32x4 acc = (aP + aQ) + aR;
#pragma unroll
                for (int r = 0; r < 4; ++r) {
                    float sc = fmaf(-2.f, acc[r], cbv);
                    int cell = rt * 4 + r;
                    bool lt = sc < m1[cell];
                    m2[cell] = fminf(m2[cell], lt ? m1[cell] : sc);
                    if (lt) { m1[cell] = sc; t1[cell] = t; }
                }
            }
        }
        __syncthreads();   // readers of buf[g&1] done; g+1 loads drained
    }

    // ---- phase 4: per-position reduce over 16 lanes; flag ambiguity ----
#pragma unroll
    for (int cell = 0; cell < 8; ++cell) {
        int rt = cell >> 2, r = cell & 3;
        float v1 = m1[cell], v2 = m2[cell];
        int i1 = t1[cell] * 16 + m;
#pragma unroll
        for (int s = 1; s < 16; s <<= 1) {
            float o1 = __shfl_xor(v1, s);
            float o2 = __shfl_xor(v2, s);
            int   oi = __shfl_xor(i1, s);
            bool take = (o1 < v1) || (o1 == v1 && oi < i1);
            float lose = take ? v1 : o1;
            if (take) { v1 = o1; i1 = oi; }
            v2 = fminf(fminf(v2, o2), lose);
        }
        if (m == 0) {
            int pos = wv * 32 + rt * 16 + q * 4 + r;
            float xs = s_xsqr[pos];
            float sx = 8.0f * sqrtf(xs) * 1.01f;       // >= sum |x_d|
            float amax = 0.00196f * sx + 0.01f;        // >= sum|x c| + margin
            float eps = 1.5f * (3.0f * 1.52587890625e-5f * 0.00196f * sx
                                + 500.f * 5.96e-8f * amax);
            float delta = 2.4e-7f * (xs + 1.0f) + 64.f * 1.2e-7f * amax;
            float W = 2.f * eps + 2.f * delta + 1e-9f;
            int flag = (v2 - v1 <= W) ? (1 << 30) : 0;
            s_idx[pos] = i1 | flag;
        }
    }
    __syncthreads();
    if (tid < POSB) {
        if (s_idx[tid] & (1 << 30)) {
            int slot = atomicAdd(&s_cnt, 1);
            s_flist[slot] = tid;
        }
    }
    __syncthreads();

    // ---- phase 5: np-exact refine of flagged positions ----
    const int cnt = s_cnt;
    for (int i = wv; i < cnt; i += 4) {
        int p = __builtin_amdgcn_readfirstlane(s_flist[i]);
        float xv = z[gbase + (long)ln * HWSZ + p];   // lane ln holds x[d=ln]
        float xs = s_xsqr[p];
        float dot[8];
#pragma unroll
        for (int j = 0; j < 8; ++j) dot[j] = 0.f;
        const float* crow = cb + (ln * 8) * DDIM;    // lane's 8 codes
        for (int dc = 0; dc < 16; ++dc) {
            float x0 = __shfl(xv, dc*4 + 0);
            float x1 = __shfl(xv, dc*4 + 1);
            float x2 = __shfl(xv, dc*4 + 2);
            float x3 = __shfl(xv, dc*4 + 3);
#pragma unroll
            for (int j = 0; j < 8; ++j) {
                float4 cv = *(const float4*)(crow + j * DDIM + dc * 4);
                dot[j] = fmaf(x0, cv.x, dot[j]);
                dot[j] = fmaf(x1, cv.y, dot[j]);
                dot[j] = fmaf(x2, cv.z, dot[j]);
                dot[j] = fmaf(x3, cv.w, dot[j]);
            }
        }
        float bv = 3.4e38f; int bi = 0;
#pragma unroll
        for (int j = 0; j < 8; ++j) {
            int k = ln * 8 + j;
            float tt = s_cbsqr[k] + xs;
            float e = fmaf(-2.f, dot[j], tt);
            if (e < bv) { bv = e; bi = k; }
        }
#pragma unroll
        for (int s = 1; s < 64; s <<= 1) {
            float ov = __shfl_xor(bv, s); int oi = __shfl_xor(bi, s);
            if (ov < bv || (ov == bv && oi < bi)) { bv = ov; bi = oi; }
        }
        if (ln == 0) s_idx[p] = bi;
    }
    __syncthreads();

    // ---- phase 6: scatter selected codes to both outputs (NCHW) ----
    {
        int p = tid & 127, hf = tid >> 7;
        int idx = s_idx[p] & 0x3FFFFFFF;
        const float4* crow4 = (const float4*)(cb + idx * DDIM + hf * 32);
        float* o0 = out + gbase + p;
        float* o1 = o0 + OUT2_OFF;
#pragma unroll
        for (int qq = 0; qq < 8; ++qq) {
            float4 v = crow4[qq];
            long db = (long)(hf * 32 + qq * 4) * HWSZ;
            o0[db]          = v.x; o0[db + HWSZ]   = v.y;
            o0[db + 2*HWSZ] = v.z; o0[db + 3*HWSZ] = v.w;
            o1[db]          = v.x; o1[db + HWSZ]   = v.y;
            o1[db + 2*HWSZ] = v.z; o1[db + 3*HWSZ] = v.w;
        }
    }
}

extern "C" void kernel_launch(void* const* d_in, const int* in_sizes, int n_in,
                              void* d_out, int out_size, void* d_ws, size_t ws_size,
                              hipStream_t stream) {
    const float* z  = (const float*)d_in[0];   // [32,64,64,64] fp32
    const float* cb = (const float*)d_in[1];   // [512,64] fp32
    float* out = (float*)d_out;                // 2 * 8388608 fp32
    unsigned short* wsb = (unsigned short*)d_ws;            // 128 KB frags
    float* wscb = (float*)((char*)d_ws + 131072);           // 2 KB cbsqr
    vq_prep<<<130, 256, 0, stream>>>(cb, wsb, wscb);
    vq_main<<<NBLK, 256, 0, stream>>>(z, cb, wsb, wscb, out);
}